// Round 5
// baseline (206.340 us; speedup 1.0000x reference)
//
#include <hip/hip_runtime.h>

// out[n,i,j] = sum_k x[n,i,k] * w[i,j,k] + b[i,j]   (N=128, D=512)
// One block per i. 64 half-chunk phases (16 j-rows x 256 k = 16KB f32 W each).
// Phase h: [issue glds(h+3)] [compute(h) MFMA] [convert(h+1) f32->bf16]
//          [stores every 4th phase] [counted vmcnt + s_barrier].
// glds 3-deep: issued at h-3, waited end of h-2 -> HBM queue never empty.
// LDS = 4*16K (f32 staging) + 2*8K (bf16) = 81920 B exactly -> 2 blocks/CU.

#define Dd 512
#define DD (512 * 512)
#define NPH 64

typedef __attribute__((ext_vector_type(8))) short bf16x8;
typedef __attribute__((ext_vector_type(4))) short bf16x4;
typedef __attribute__((ext_vector_type(4))) float f32x4;

__device__ __forceinline__ short f2bf(float f) {
    unsigned u = __builtin_bit_cast(unsigned, f);
    u += 0x7FFFu + ((u >> 16) & 1u);      // RNE
    return (short)(u >> 16);
}

__device__ __forceinline__ void glds16(const float* g, float* l) {
    __builtin_amdgcn_global_load_lds(
        (const __attribute__((address_space(1))) void*)g,
        (__attribute__((address_space(3))) void*)l, 16, 0, 0);
}

__global__ __launch_bounds__(512, 4)
void linear3d_kernel(const float* __restrict__ x,
                     const float* __restrict__ w,
                     const float* __restrict__ b,
                     float* __restrict__ out) {
    const int i    = blockIdx.x;
    const int tid  = threadIdx.x;
    const int lane = tid & 63;
    const int wid  = tid >> 6;            // wave owns n-rows [wid*16, wid*16+16)

    __shared__ float f32h[4][4096];       // 4 x 16KB f32 half-chunk (glds dst)
    __shared__ short b16h[2][4096];       // 2 x 8KB swizzled bf16 half-chunk

    const float* xi = x + (size_t)i * Dd;             // x[n,i,k] = xi[n*DD + k]
    const float* wi = w + (size_t)i * DD;             // w[i,j,k] = wi[j*Dd + k]
    const int row16 = lane & 15;
    const int cg16  = (lane >> 4) * 16;

    // ---- issue glds for half-chunks 0..2 (each: 16 rows, one row per instr)
    #pragma unroll
    for (int h0 = 0; h0 < 3; ++h0) {
        const float* src = wi + (size_t)(h0 >> 1) * (16 * Dd) + (h0 & 1) * 256;
        #pragma unroll
        for (int q = 0; q < 2; ++q) {
            int rl = wid * 2 + q;
            glds16(src + (size_t)rl * Dd + lane * 4, &f32h[h0][rl * 256]);
        }
    }

    // ---- X staging: 8 rounds of 16 n-rows via b16h scratch (16KB, 1024B rows)
    short* xs = &b16h[0][0];
    bf16x8 xf[16];
    for (int r = 0; r < 8; ++r) {
        __syncthreads();
        #pragma unroll
        for (int p = 0; p < 4; ++p) {
            int idx4 = tid + p * 512;     // 16 rows x 128 float4
            int row = idx4 >> 7, c4 = idx4 & 127;
            float4 v = *(const float4*)(xi + (size_t)(r * 16 + row) * DD + c4 * 4);
            bf16x4 hh = { f2bf(v.x), f2bf(v.y), f2bf(v.z), f2bf(v.w) };
            int byte = (row * 1024 + c4 * 8) ^ ((row & 7) << 4);
            *(bf16x4*)((char*)xs + byte) = hh;
        }
        __syncthreads();
        if (wid == r) {
            #pragma unroll
            for (int s = 0; s < 16; ++s) {
                int byte = (row16 * 1024 + s * 64 + cg16) ^ ((row16 & 7) << 4);
                xf[s] = *(const bf16x8*)((const char*)xs + byte);
            }
        }
    }
    __syncthreads();   // staging reads done; glds(0..2) fully drained here

// convert half-chunk: f32h[FS] (16 rows x 256 f32) -> b16h[BS] swizzled
#define CONVERT(FS, BS) do {                                                   \
    _Pragma("unroll")                                                          \
    for (int p = 0; p < 2; ++p) {                                              \
        float4 v = *(const float4*)(&f32h[FS][p * 2048 + tid * 4]);            \
        int rw = p * 8 + wid;                                                  \
        bf16x4 hh = { f2bf(v.x), f2bf(v.y), f2bf(v.z), f2bf(v.w) };            \
        int byte = (rw * 512 + lane * 8) ^ ((rw & 7) << 4);                    \
        *(bf16x4*)((char*)&b16h[BS][0] + byte) = hh;                           \
    }                                                                          \
} while (0)

#define GLDS_ISSUE(Hn, FB) do {                                                \
    const float* src_ = wi + (size_t)((Hn) >> 1) * (16 * Dd) + ((Hn) & 1) * 256; \
    _Pragma("unroll")                                                          \
    for (int q = 0; q < 2; ++q) {                                              \
        int rl = wid * 2 + q;                                                  \
        glds16(src_ + (size_t)rl * Dd + lane * 4, &f32h[FB][rl * 256]);        \
    }                                                                          \
} while (0)

#define COMPUTE(U, ACC) do {                                                   \
    _Pragma("unroll")                                                          \
    for (int s = 0; s < 8; ++s) {                                              \
        int byte = (row16 * 512 + s * 64 + cg16) ^ ((row16 & 7) << 4);         \
        bf16x8 wf = *(const bf16x8*)((const char*)&b16h[(U) & 1][0] + byte);   \
        ACC = __builtin_amdgcn_mfma_f32_16x16x32_bf16(                         \
            xf[((U) & 1) * 8 + s], wf, ACC, 0, 0, 0);                          \
    }                                                                          \
} while (0)

#define ENDPH(VM) do {                                                         \
    asm volatile("s_waitcnt vmcnt(" #VM ") lgkmcnt(0)" ::: "memory");          \
    __builtin_amdgcn_s_barrier();                                              \
} while (0)

// phases u=0..2: glds(h+3) -> f32h[(U+3)&3]; compute b16h[U&1]; convert(h+1)
#define PH(H, U, ACC, VM) do {                                                 \
    int h_ = (H);                                                              \
    if (h_ + 3 < NPH) GLDS_ISSUE(h_ + 3, ((U) + 3) & 3);                       \
    COMPUTE(U, ACC);                                                           \
    CONVERT(((U) + 1) & 3, ((U) + 1) & 1);                                     \
    ENDPH(VM);                                                                 \
} while (0)

// phase u=3: bias loads FIRST (so their auto-wait leaves glds in flight),
// then glds, compute(acc1), convert, chunk-pair stores.
#define PH3(H, VM) do {                                                        \
    int h_ = (H);                                                              \
    int j0 = (h_ - 3) * 8 + row16;                                             \
    float bias0 = b[i * Dd + j0];                                              \
    float bias1 = b[i * Dd + j0 + 16];                                         \
    if (h_ + 3 < NPH) GLDS_ISSUE(h_ + 3, 2);                                   \
    COMPUTE(3, acc1);                                                          \
    if (h_ + 1 < NPH) CONVERT(0, 0);                                           \
    _Pragma("unroll")                                                          \
    for (int r_ = 0; r_ < 4; ++r_) {                                           \
        int n_ = wid * 16 + (lane >> 4) * 4 + r_;                              \
        float* op_ = out + (size_t)i * Dd + (size_t)n_ * DD;                   \
        op_[j0]      = acc0[r_] + bias0;                                       \
        op_[j0 + 16] = acc1[r_] + bias1;                                       \
    }                                                                          \
    ENDPH(VM);                                                                 \
} while (0)

    // ---- prologue convert(0), then enter steady loop
    CONVERT(0, 0);
    __syncthreads();

    f32x4 acc0 = {0.f, 0.f, 0.f, 0.f}, acc1 = {0.f, 0.f, 0.f, 0.f};

    // t=0: fewer prior stores -> tighter waits (vm over-approx is unsafe here)
    PH (0, 0, acc0, 2);
    PH (1, 1, acc0, 2);
    PH (2, 2, acc1, 2);
    PH3(3, 12);

    for (int t = 1; t < 15; ++t) {
        int h = t * 4;
        acc0 = (f32x4){0.f, 0.f, 0.f, 0.f};
        PH (h,     0, acc0, 10);
        PH (h + 1, 1, acc0, 2);
        acc1 = (f32x4){0.f, 0.f, 0.f, 0.f};
        PH (h + 2, 2, acc1, 2);
        PH3(h + 3, 12);
    }

    // t=15 tail: no glds(64+); must fully drain before last converts
    acc0 = (f32x4){0.f, 0.f, 0.f, 0.f};
    PH (60, 0, acc0, 10);
    PH (61, 1, acc0, 0);
    acc1 = (f32x4){0.f, 0.f, 0.f, 0.f};
    PH (62, 2, acc1, 0);
    PH3(63, 0);

#undef PH3
#undef PH
#undef ENDPH
#undef COMPUTE
#undef GLDS_ISSUE
#undef CONVERT
}

extern "C" void kernel_launch(void* const* d_in, const int* in_sizes, int n_in,
                              void* d_out, int out_size, void* d_ws, size_t ws_size,
                              hipStream_t stream) {
    const float* x = (const float*)d_in[0];
    const float* w = (const float*)d_in[1];
    const float* b = (const float*)d_in[2];
    float* out = (float*)d_out;
    linear3d_kernel<<<dim3(Dd), dim3(512), 0, stream>>>(x, w, b, out);
}

// Round 6
// 205.612 us; speedup vs baseline: 1.0035x; 1.0035x over previous
//
#include <hip/hip_runtime.h>

// out[n,i,j] = sum_k x[n,i,k] * w[i,j,k] + b[i,j]   (N=128, D=512)
// One block per i. Chunks of 16 j-rows, full K. f32 ring of 2 (glds targets,
// SELF-CONVERT: wave w gldses and converts only its own rows -> no cross-wave
// sync on the ring), single bf16 buffer (2 barriers/chunk). Counted vmcnt
// (in-order retirement): steady 14, edges 9/10. LDS = 81920 B -> 2 blocks/CU.

#define Dd 512
#define DD (512 * 512)

typedef __attribute__((ext_vector_type(8))) short bf16x8;
typedef __attribute__((ext_vector_type(4))) short bf16x4;
typedef __attribute__((ext_vector_type(4))) float f32x4;

__device__ __forceinline__ short f2bf(float f) {
    unsigned u = __builtin_bit_cast(unsigned, f);
    u += 0x7FFFu + ((u >> 16) & 1u);      // RNE
    return (short)(u >> 16);
}

__device__ __forceinline__ void glds16(const float* g, float* l) {
    __builtin_amdgcn_global_load_lds(
        (const __attribute__((address_space(1))) void*)g,
        (__attribute__((address_space(3))) void*)l, 16, 0, 0);
}

__global__ __launch_bounds__(512, 4)
void linear3d_kernel(const float* __restrict__ x,
                     const float* __restrict__ w,
                     const float* __restrict__ b,
                     float* __restrict__ out) {
    const int i    = blockIdx.x;
    const int tid  = threadIdx.x;
    const int lane = tid & 63;
    const int wid  = tid >> 6;
    const int row16 = lane & 15;
    const int cg    = lane >> 4;

    __shared__ float f32r[2][8192];   // 64 KB ring: W chunk f32 (glds dst)
    __shared__ short b16s[8192];      // 16 KB: swizzled bf16 W chunk / X scratch

    const float* xi = x + (size_t)i * Dd;     // x[n,i,k] = xi[n*DD + k]
    const float* wi = w + (size_t)i * DD;     // w[i,j,k] = wi[j*Dd + k]

    // ---- glds W(0)->ring0, W(1)->ring1 (wave w owns floats [w*1024,+1024)
    //      = rows 2w,2w+1 of the chunk)
    #pragma unroll
    for (int q = 0; q < 4; ++q) { int t = wid * 4 + q;
        glds16(wi + t * 256 + lane * 4, &f32r[0][t * 256]); }
    #pragma unroll
    for (int q = 0; q < 4; ++q) { int t = wid * 4 + q;
        glds16(wi + 8192 + t * 256 + lane * 4, &f32r[1][t * 256]); }

    // ---- X staging: 8 rounds of 16 n-rows via b16s -> xf[16] fragments
    bf16x8 xf[16];
    for (int r = 0; r < 8; ++r) {
        __syncthreads();
        #pragma unroll
        for (int p = 0; p < 4; ++p) {
            int idx4 = tid + p * 512;         // 16 rows x 128 float4
            int row = idx4 >> 7, c4 = idx4 & 127;
            float4 v = *(const float4*)(xi + (size_t)(r * 16 + row) * DD + c4 * 4);
            bf16x4 h = { f2bf(v.x), f2bf(v.y), f2bf(v.z), f2bf(v.w) };
            int byte = (row * 1024 + c4 * 8) ^ ((row & 7) << 4);
            *(bf16x4*)((char*)b16s + byte) = h;
        }
        __syncthreads();
        if (wid == r) {
            #pragma unroll
            for (int s = 0; s < 16; ++s) {
                int byte = (row16 * 1024 + s * 64 + cg * 16) ^ ((row16 & 7) << 4);
                xf[s] = *(const bf16x8*)((const char*)b16s + byte);
            }
        }
    }
    __syncthreads();                          // b16s free; staging loads retired

// convert-write one float4 (round q) of this wave's rows into swizzled b16s
#define CVTW(V, q) do {                                                        \
    int row_  = 2 * wid + ((q) >> 1);                                          \
    int byte_ = (row_ * 1024 + ((q) & 1) * 512 + lane * 8) ^ ((row_ & 7) << 4);\
    bf16x4 h_ = { f2bf(V.x), f2bf(V.y), f2bf(V.z), f2bf(V.w) };                \
    *(bf16x4*)((char*)b16s + byte_) = h_;                                      \
} while (0)

    // ---- prologue convert(0): ring0 -> b16s; then glds(2)->ring0; bias(0)
    {
        asm volatile("s_waitcnt vmcnt(5)" ::: "memory");   // g(0) retired
        __builtin_amdgcn_sched_barrier(0);
        float4 v0 = *(const float4*)(&f32r[0][wid * 1024 +   0 + lane * 4]);
        float4 v1 = *(const float4*)(&f32r[0][wid * 1024 + 256 + lane * 4]);
        float4 v2 = *(const float4*)(&f32r[0][wid * 1024 + 512 + lane * 4]);
        float4 v3 = *(const float4*)(&f32r[0][wid * 1024 + 768 + lane * 4]);
        asm volatile("s_waitcnt lgkmcnt(0)" ::: "memory"); // reads in regs
        __builtin_amdgcn_sched_barrier(0);
        #pragma unroll
        for (int q = 0; q < 4; ++q) { int t = wid * 4 + q;
            glds16(wi + 2 * 8192 + t * 256 + lane * 4, &f32r[0][t * 256]); }
        CVTW(v0, 0); CVTW(v1, 1); CVTW(v2, 2); CVTW(v3, 3);
    }
    float bias = b[i * Dd + row16];
    asm volatile("s_waitcnt lgkmcnt(0)" ::: "memory");
    __builtin_amdgcn_s_barrier();

    // Per-wave vmem order: prologue [g0 g1 g2 bias0], chunk c [st(c)x4
    // g(c+3)x4 bias(c+1)].  In-order retirement => newer-than-g(c+1) counts:
    // c=0: g2x4+bias0+st0x4 = 9; c=1..29: bias(c-1)+st(c-1)x4+g(c+2)x4+
    // bias(c)+st(c)x4 = 14; c=30 (no g33): 10.
#define CHUNK_BODY(c, VMSTR, DO_GLDS, DO_CONV) do {                            \
    f32x4 accA = {0.f, 0.f, 0.f, 0.f}, accB = {0.f, 0.f, 0.f, 0.f};           \
    _Pragma("unroll")                                                          \
    for (int s = 0; s < 16; s += 2) {                                          \
        int byA = (row16 * 1024 + s * 64 + cg * 16) ^ ((row16 & 7) << 4);      \
        int byB = (row16 * 1024 + (s + 1) * 64 + cg * 16) ^ ((row16 & 7) << 4);\
        bf16x8 wfA = *(const bf16x8*)((const char*)b16s + byA);                \
        bf16x8 wfB = *(const bf16x8*)((const char*)b16s + byB);                \
        accA = __builtin_amdgcn_mfma_f32_16x16x32_bf16(xf[s], wfA, accA, 0, 0, 0);     \
        accB = __builtin_amdgcn_mfma_f32_16x16x32_bf16(xf[s + 1], wfB, accB, 0, 0, 0); \
    }                                                                          \
    { int j = (c) * 16 + row16;                                                \
      _Pragma("unroll")                                                        \
      for (int r_ = 0; r_ < 4; ++r_) {                                         \
          int n_ = wid * 16 + cg * 4 + r_;                                     \
          out[(size_t)i * Dd + (size_t)n_ * DD + j] = accA[r_] + accB[r_] + bias; \
      } }                                                                      \
    asm volatile("s_waitcnt lgkmcnt(0)" ::: "memory");                         \
    __builtin_amdgcn_s_barrier();                                              \
    if (DO_CONV) {                                                             \
        const float* fb = &f32r[((c) + 1) & 1][0];                             \
        asm volatile("s_waitcnt " VMSTR ::: "memory");                         \
        __builtin_amdgcn_sched_barrier(0);                                     \
        float4 v0 = *(const float4*)(fb + wid * 1024 +   0 + lane * 4);        \
        float4 v1 = *(const float4*)(fb + wid * 1024 + 256 + lane * 4);        \
        float4 v2 = *(const float4*)(fb + wid * 1024 + 512 + lane * 4);        \
        float4 v3 = *(const float4*)(fb + wid * 1024 + 768 + lane * 4);        \
        asm volatile("s_waitcnt lgkmcnt(0)" ::: "memory");                     \
        __builtin_amdgcn_sched_barrier(0);                                     \
        if (DO_GLDS) {                                                         \
            const float* gs = wi + (size_t)((c) + 3) * 8192;                   \
            float* lb = &f32r[((c) + 1) & 1][0];                               \
            _Pragma("unroll")                                                  \
            for (int q = 0; q < 4; ++q) { int t = wid * 4 + q;                 \
                glds16(gs + t * 256 + lane * 4, lb + t * 256); }               \
        }                                                                      \
        bias = b[i * Dd + ((c) + 1) * 16 + row16];                             \
        CVTW(v0, 0); CVTW(v1, 1); CVTW(v2, 2); CVTW(v3, 3);                    \
        asm volatile("s_waitcnt lgkmcnt(0)" ::: "memory");                     \
        __builtin_amdgcn_s_barrier();                                          \
    }                                                                          \
} while (0)

    CHUNK_BODY(0, "vmcnt(9)", true, true);
    for (int c = 1; c <= 29; ++c)
        CHUNK_BODY(c, "vmcnt(14)", (c + 3 < 32), true);
    CHUNK_BODY(30, "vmcnt(10)", false, true);
    CHUNK_BODY(31, "vmcnt(0)", false, false);

#undef CHUNK_BODY
#undef CVTW
}

extern "C" void kernel_launch(void* const* d_in, const int* in_sizes, int n_in,
                              void* d_out, int out_size, void* d_ws, size_t ws_size,
                              hipStream_t stream) {
    const float* x = (const float*)d_in[0];
    const float* w = (const float*)d_in[1];
    const float* b = (const float*)d_in[2];
    float* out = (float*)d_out;
    linear3d_kernel<<<dim3(Dd), dim3(512), 0, stream>>>(x, w, b, out);
}